// Round 10
// baseline (383.395 us; speedup 1.0000x reference)
//
#include <hip/hip_runtime.h>

typedef _Float16 f16;
typedef _Float16 f16x4 __attribute__((ext_vector_type(4)));
typedef _Float16 f16x8 __attribute__((ext_vector_type(8)));
typedef float    f32x4 __attribute__((ext_vector_type(4)));

// ws layout (bytes)
#define OFF_WHP   0u          // f16 [5][16nt][8kk][64lane][8e]   = 655360 B
#define OFF_WLP   655360u     // f16 [8kk][64lane][8e]            = 8192 B
#define OFF_W0P   663552u     // f32 [8kk][64lane][8e][4i]        = 65536 B
#define OFF_B0P   729088u     // f32 [8kk][64lane][8e]            = 16384 B
#define OFF_GP    745472u     // f32 [3j][8kk][64lane][8e]        = 49152 B
#define OFF_BHP   794624u     // f32 [5l][16nt][64lane][4r]       = 81920 B

// k-slot map: slot (kk, lane-group g, elem e) -> k = (2kk+(e>>2))*16+4g+(e&3).
// Applied identically to A (weights, prepacked) and B (activations), so the
// MFMA D-output (n = nt*16+4g+r) lands exactly in next layer's B-slot
// (kk'=nt>>1, e'=(nt&1)*4+r): lane-local layer transitions.
__device__ __forceinline__ int phi(int kk, int g, int e){
  return (kk*2 + (e>>2))*16 + g*4 + (e&3);
}

__device__ __forceinline__ float tanh_fast(float z){
  float e = __builtin_amdgcn_exp2f(z * 2.885390081777927f);
  return 1.f - 2.f*__builtin_amdgcn_rcpf(e + 1.f);
}

__global__ void prepack(const float* __restrict__ W0, const float* __restrict__ b0,
                        const float* __restrict__ Wh, const float* __restrict__ bh,
                        const float* __restrict__ Wl, unsigned char* __restrict__ ws){
  int tid = blockIdx.x*256 + threadIdx.x;
  f16*   whp = (f16*)(ws + OFF_WHP);
  f16*   wlp = (f16*)(ws + OFF_WLP);
  float* w0p = (float*)(ws + OFF_W0P);
  float* b0p = (float*)(ws + OFF_B0P);
  float* gp  = (float*)(ws + OFF_GP);
  float* bhp = (float*)(ws + OFF_BHP);
  if (tid < 327680){                      // Wh fragments, f16
    int e=tid&7, lane=(tid>>3)&63, kk=(tid>>9)&7, nt=(tid>>12)&15, l=tid>>16;
    int k = phi(kk, lane>>4, e);
    int n = nt*16 + (lane&15);
    whp[tid] = (f16)Wh[(l*256 + k)*256 + n];
  } else if (tid < 331776){               // Wl fragments (N padded 3->16), f16
    int t = tid - 327680;
    int e=t&7, lane=(t>>3)&63, kk=t>>9;
    int k = phi(kk, lane>>4, e);
    int n = lane&15;
    wlp[t] = (n<3) ? (f16)Wl[k*3+n] : (f16)0.f;
  } else if (tid < 335872){               // W0 columns + b0 in slot order, f32
    int t = tid - 331776;
    int e=t&7, lane=(t>>3)&63, kk=t>>9;
    int k = phi(kk, lane>>4, e);
    #pragma unroll
    for(int i=0;i<4;i++) w0p[t*4+i] = W0[i*256+k];
    b0p[t] = b0[k];
  } else if (tid < 348160){               // g_j = W0[j,:] @ Wh[0], slot order, f32
    int t = tid - 335872;
    int e=t&7, lane=(t>>3)&63, kk=(t>>9)&7, j=t>>12;
    int k = phi(kk, lane>>4, e);
    float acc = 0.f;
    for(int k0=0;k0<256;k0++) acc = fmaf(W0[j*256+k0], Wh[k0*256+k], acc);
    gp[t] = acc;
  } else if (tid < 368640){               // bh in D-layout order, f32
    int t = tid - 348160;
    int r=t&3, lane=(t>>2)&63, nt=(t>>8)&15, l=t>>12;
    bhp[t] = bh[l*256 + nt*16 + (lane>>4)*4 + r];
  }
}

// Lane-local mask layout: writer lane (s,g) of wave0 produces exactly the mask
// set reader lane (s,g) of waves 1..3 needs (n = nt*16+4g+r both sides).
__device__ __forceinline__ int moff(int lane, int kk){
  return lane*128 + ((kk ^ (lane & 7)) << 4);
}

// R10: explicit SW-pipelined weight prefetch. R9 showed the kernel is
// latency-bound on the L2 weight stream (~130 cyc/MFMA, MfmaUtil 18%, all BW
// counters low): only ~2 loads in flight per wave. Ring-buffered fragment
// prefetch (distance 3 tangent / 2 primal, static indices under full unroll)
// keeps 16-24 loads in flight so ~225cyc L2 latency hides under MFMA+VALU.
__global__ __launch_bounds__(256, 2) void velcurl(
    const float* __restrict__ x, const unsigned char* __restrict__ ws,
    float* __restrict__ out){
  __shared__ __align__(16) char mbuf[2][2][8192];  // [dbuf][tile] masks
  __shared__ float outt[2][3][3][16];              // [tile][j][n][s] Jacobian rows

  const int lane  = threadIdx.x & 63;
  const int w     = threadIdx.x >> 6;   // 0 = primal, 1..3 = tangent j=w-1
  const int s     = lane & 15;          // sample column
  const int sbase = blockIdx.x << 5;    // 32 samples per block

  const f16x8* __restrict__ whp = (const f16x8*)(ws + OFF_WHP);
  const f16x8* __restrict__ wlp = (const f16x8*)(ws + OFF_WLP);
  const f32x4* __restrict__ w0p = (const f32x4*)(ws + OFF_W0P);
  const float* __restrict__ b0p = (const float*)(ws + OFF_B0P);
  const float* __restrict__ gp  = (const float*)(ws + OFF_GP);
  const f32x4* __restrict__ bhp = (const f32x4*)(ws + OFF_BHP);

  f16x8 st[2][8];    // primal h frags / tangent bf (B-slot order), per tile
  f16x8 nst[2][8];   // next-state (primal h / unmasked tangent preact)

  // ---- phase 0: primal layer0 + Wh0, masks0 -> mbuf[0] ----
  if (w==0){
    // issue Wh0 prefetch (ring 2) BEFORE layer-0 compute: latency hidden there
    f16x8 F[2][8]; f32x4 BV[2];
    #pragma unroll
    for(int q=0;q<2;q++){
      #pragma unroll
      for(int kk=0;kk<8;kk++) F[q][kk] = whp[(q*8+kk)*64+lane];
      BV[q] = bhp[q*64+lane];
    }
    const f32x4 xv0 = ((const f32x4*)x)[sbase + s];
    const f32x4 xv1 = ((const f32x4*)x)[sbase + 16 + s];
    #pragma unroll
    for(int kk=0;kk<8;kk++){
      f16x8 v0, v1;
      #pragma unroll
      for(int e=0;e<8;e++){
        f32x4 wv = w0p[(kk*64+lane)*8+e];
        float b  = b0p[(kk*64+lane)*8+e];
        v0[e] = (f16)fmaf(xv0[3],wv[3], fmaf(xv0[2],wv[2], fmaf(xv0[1],wv[1], fmaf(xv0[0],wv[0], b))));
        v1[e] = (f16)fmaf(xv1[3],wv[3], fmaf(xv1[2],wv[2], fmaf(xv1[1],wv[1], fmaf(xv1[0],wv[0], b))));
      }
      st[0][kk] = v0; st[1][kk] = v1;
    }
    f16x8 mc0, mc1;
    #pragma unroll
    for(int nt=0;nt<16;nt++){
      const int cs = nt & 1;          // ring 2, static under unroll
      f32x4 a0 = {0.f,0.f,0.f,0.f}, a1 = {0.f,0.f,0.f,0.f};
      #pragma unroll
      for(int kk=0;kk<8;kk++){
        a0 = __builtin_amdgcn_mfma_f32_16x16x32_f16(F[cs][kk], st[0][kk], a0, 0,0,0);
        a1 = __builtin_amdgcn_mfma_f32_16x16x32_f16(F[cs][kk], st[1][kk], a1, 0,0,0);
      }
      f32x4 bv = BV[cs];
      if (nt < 14){                   // prefetch nt+2 into freed slot
        #pragma unroll
        for(int kk=0;kk<8;kk++) F[cs][kk] = whp[((nt+2)*8+kk)*64+lane];
        BV[cs] = bhp[(nt+2)*64+lane];
      }
      #pragma unroll
      for(int r=0;r<4;r++){
        float h0 = tanh_fast(a0[r]+bv[r]);
        float h1 = tanh_fast(a1[r]+bv[r]);
        nst[0][nt>>1][(nt&1)*4+r] = (f16)h0;
        nst[1][nt>>1][(nt&1)*4+r] = (f16)h1;
        mc0[(nt&1)*4+r] = (f16)(1.f - h0*h0);
        mc1[(nt&1)*4+r] = (f16)(1.f - h1*h1);
      }
      if (nt&1){
        *(f16x8*)(&mbuf[0][0][0] + moff(lane, nt>>1)) = mc0;
        *(f16x8*)(&mbuf[0][1][0] + moff(lane, nt>>1)) = mc1;
      }
    }
    #pragma unroll
    for(int kk=0;kk<8;kk++){ st[0][kk]=nst[0][kk]; st[1][kk]=nst[1][kk]; }
  }
  __syncthreads();

  // ---- phases 1..4: primal layer p || tangent layer p (uses masks p-1) ----
  #pragma unroll 1
  for(int p=1;p<5;p++){
    const f16x8* wl = whp + p*8192;
    if (w==0){
      const f32x4* bp = bhp + p*1024;
      f16x8 F[2][8]; f32x4 BV[2];
      #pragma unroll
      for(int q=0;q<2;q++){
        #pragma unroll
        for(int kk=0;kk<8;kk++) F[q][kk] = wl[(q*8+kk)*64+lane];
        BV[q] = bp[q*64+lane];
      }
      f16x8 mc0, mc1;
      #pragma unroll
      for(int nt=0;nt<16;nt++){
        const int cs = nt & 1;
        f32x4 a0 = {0.f,0.f,0.f,0.f}, a1 = {0.f,0.f,0.f,0.f};
        #pragma unroll
        for(int kk=0;kk<8;kk++){
          a0 = __builtin_amdgcn_mfma_f32_16x16x32_f16(F[cs][kk], st[0][kk], a0, 0,0,0);
          a1 = __builtin_amdgcn_mfma_f32_16x16x32_f16(F[cs][kk], st[1][kk], a1, 0,0,0);
        }
        f32x4 bv = BV[cs];
        if (nt < 14){
          #pragma unroll
          for(int kk=0;kk<8;kk++) F[cs][kk] = wl[((nt+2)*8+kk)*64+lane];
          BV[cs] = bp[(nt+2)*64+lane];
        }
        #pragma unroll
        for(int r=0;r<4;r++){
          float h0 = tanh_fast(a0[r]+bv[r]);
          float h1 = tanh_fast(a1[r]+bv[r]);
          nst[0][nt>>1][(nt&1)*4+r] = (f16)h0;
          nst[1][nt>>1][(nt&1)*4+r] = (f16)h1;
          mc0[(nt&1)*4+r] = (f16)(1.f - h0*h0);
          mc1[(nt&1)*4+r] = (f16)(1.f - h1*h1);
        }
        if (nt&1){
          *(f16x8*)(&mbuf[p&1][0][0] + moff(lane, nt>>1)) = mc0;
          *(f16x8*)(&mbuf[p&1][1][0] + moff(lane, nt>>1)) = mc1;
        }
      }
      #pragma unroll
      for(int kk=0;kk<8;kk++){ st[0][kk]=nst[0][kk]; st[1][kk]=nst[1][kk]; }
    } else {
      const char* mb0 = &mbuf[(p-1)&1][0][0];
      const char* mb1 = &mbuf[(p-1)&1][1][0];
      // ring-3 weight prefetch, issued before the mask/bf build so loads are
      // already in flight during the VALU work
      f16x8 F[3][8];
      #pragma unroll
      for(int q=0;q<3;q++)
        #pragma unroll
        for(int kk=0;kk<8;kk++) F[q][kk] = wl[(q*8+kk)*64+lane];
      if (p==1){
        const int j = w-1;
        const f32x4* gpv = (const f32x4*)gp;
        #pragma unroll
        for(int kk=0;kk<8;kk++){
          f16x8 m80 = *(const f16x8*)(mb0 + moff(lane, kk));
          f16x8 m81 = *(const f16x8*)(mb1 + moff(lane, kk));
          f32x4 g0 = gpv[((j*8+kk)*64+lane)*2+0];
          f32x4 g1 = gpv[((j*8+kk)*64+lane)*2+1];
          f16x8 v0, v1;
          #pragma unroll
          for(int e=0;e<8;e++){
            float gv = (e<4) ? g0[e&3] : g1[e&3];
            v0[e] = (f16)((float)m80[e] * gv);
            v1[e] = (f16)((float)m81[e] * gv);
          }
          st[0][kk] = v0; st[1][kk] = v1;
        }
      } else {
        #pragma unroll
        for(int kk=0;kk<8;kk++){
          f16x8 m80 = *(const f16x8*)(mb0 + moff(lane, kk));
          f16x8 m81 = *(const f16x8*)(mb1 + moff(lane, kk));
          st[0][kk] = m80 * nst[0][kk];
          st[1][kk] = m81 * nst[1][kk];
        }
      }
      #pragma unroll
      for(int nt=0;nt<16;nt++){
        const int cs = nt % 3;        // static under unroll
        f32x4 a0 = {0.f,0.f,0.f,0.f}, a1 = {0.f,0.f,0.f,0.f};
        #pragma unroll
        for(int kk=0;kk<8;kk++){
          a0 = __builtin_amdgcn_mfma_f32_16x16x32_f16(F[cs][kk], st[0][kk], a0, 0,0,0);
          a1 = __builtin_amdgcn_mfma_f32_16x16x32_f16(F[cs][kk], st[1][kk], a1, 0,0,0);
        }
        if (nt < 13){                 // prefetch nt+3 into freed slot
          #pragma unroll
          for(int kk=0;kk<8;kk++) F[cs][kk] = wl[((nt+3)*8+kk)*64+lane];
        }
        #pragma unroll
        for(int r=0;r<4;r++){
          nst[0][nt>>1][(nt&1)*4+r] = (f16)a0[r];
          nst[1][nt>>1][(nt&1)*4+r] = (f16)a1[r];
        }
      }
    }
    __syncthreads();
  }

  // ---- phase 5: tangent final (mask4 in mbuf[0]) -> Wl, rows to LDS ----
  if (w>0){
    const char* mb0 = &mbuf[0][0][0];
    const char* mb1 = &mbuf[0][1][0];
    f16x8 F[8];
    #pragma unroll
    for(int kk=0;kk<8;kk++) F[kk] = wlp[kk*64+lane];   // preload all 8
    f32x4 a0 = {0.f,0.f,0.f,0.f}, a1 = {0.f,0.f,0.f,0.f};
    #pragma unroll
    for(int kk=0;kk<8;kk++){
      f16x8 m80 = *(const f16x8*)(mb0 + moff(lane, kk));
      f16x8 m81 = *(const f16x8*)(mb1 + moff(lane, kk));
      a0 = __builtin_amdgcn_mfma_f32_16x16x32_f16(F[kk], m80 * nst[0][kk], a0, 0,0,0);
      a1 = __builtin_amdgcn_mfma_f32_16x16x32_f16(F[kk], m81 * nst[1][kk], a1, 0,0,0);
    }
    // D: col=lane&15=s, row=(lane>>4)*4+reg -> lanes 0..15 hold rows 0..3
    if (lane<16){
      outt[0][w-1][0][lane] = a0[0];
      outt[0][w-1][1][lane] = a0[1];
      outt[0][w-1][2][lane] = a0[2];
      outt[1][w-1][0][lane] = a1[0];
      outt[1][w-1][1][lane] = a1[1];
      outt[1][w-1][2][lane] = a1[2];
    }
  }
  __syncthreads();

  if (w==0 && lane<32){
    const int t = lane>>4, ss = lane&15;
    const int so = (sbase + lane)*3;
    out[so+0] = outt[t][1][2][ss] - outt[t][2][1][ss];  // da2/dx1 - da1/dx2
    out[so+1] = outt[t][2][0][ss] - outt[t][0][2][ss];  // da0/dx2 - da2/dx0
    out[so+2] = outt[t][0][1][ss] - outt[t][1][0][ss];  // da1/dx0 - da0/dx1
  }
}

extern "C" void kernel_launch(void* const* d_in, const int* in_sizes, int n_in,
                              void* d_out, int out_size, void* d_ws, size_t ws_size,
                              hipStream_t stream){
  const float* x  = (const float*)d_in[0];
  const float* W0 = (const float*)d_in[1];
  const float* b0 = (const float*)d_in[2];
  const float* Wh = (const float*)d_in[3];
  const float* bh = (const float*)d_in[4];
  const float* Wl = (const float*)d_in[5];
  // d_in[6] = bl: constant offset of a, curl kills it.
  prepack<<<1440, 256, 0, stream>>>(W0, b0, Wh, bh, Wl, (unsigned char*)d_ws);
  velcurl<<<2048, 256, 0, stream>>>(x, (const unsigned char*)d_ws, (float*)d_out);
}

// Round 11
// 376.497 us; speedup vs baseline: 1.0183x; 1.0183x over previous
//
#include <hip/hip_runtime.h>

typedef _Float16 f16;
typedef _Float16 f16x8 __attribute__((ext_vector_type(8)));
typedef float    f32x4 __attribute__((ext_vector_type(4)));

// ws layout (bytes)
#define OFF_WHP   0u          // f16 [5][16nt][8kk][64lane][8e]   = 655360 B
#define OFF_WLP   655360u     // f16 [8kk][64lane][8e]            = 8192 B
#define OFF_W0P   663552u     // f32 [8kk][64lane][8e][4i]        = 65536 B
#define OFF_B0P   729088u     // f32 [8kk][64lane][8e]            = 16384 B
#define OFF_GP    745472u     // f32 [3j][8kk][64lane][8e]        = 49152 B
#define OFF_BHP   794624u     // f32 [5l][16nt][64lane][4r]       = 81920 B

// k-slot map: slot (kk, lane-group g, elem e) -> k = (2kk+(e>>2))*16+4g+(e&3).
// Same map on A (prepacked weights) and B (activations): MFMA D-output
// (n = nt*16+4g+r) lands exactly in next layer's B-slot (kk'=nt>>1,
// e'=(nt&1)*4+r) -> lane-local layer transitions.
__device__ __forceinline__ int phi(int kk, int g, int e){
  return (kk*2 + (e>>2))*16 + g*4 + (e&3);
}

__device__ __forceinline__ float tanh_fast(float z){
  float e = __builtin_amdgcn_exp2f(z * 2.885390081777927f);
  return 1.f - 2.f*__builtin_amdgcn_rcpf(e + 1.f);
}

__global__ void prepack(const float* __restrict__ W0, const float* __restrict__ b0,
                        const float* __restrict__ Wh, const float* __restrict__ bh,
                        const float* __restrict__ Wl, unsigned char* __restrict__ ws){
  int tid = blockIdx.x*256 + threadIdx.x;
  f16*   whp = (f16*)(ws + OFF_WHP);
  f16*   wlp = (f16*)(ws + OFF_WLP);
  float* w0p = (float*)(ws + OFF_W0P);
  float* b0p = (float*)(ws + OFF_B0P);
  float* gp  = (float*)(ws + OFF_GP);
  float* bhp = (float*)(ws + OFF_BHP);
  if (tid < 327680){                      // Wh fragments, f16
    int e=tid&7, lane=(tid>>3)&63, kk=(tid>>9)&7, nt=(tid>>12)&15, l=tid>>16;
    int k = phi(kk, lane>>4, e);
    int n = nt*16 + (lane&15);
    whp[tid] = (f16)Wh[(l*256 + k)*256 + n];
  } else if (tid < 331776){               // Wl fragments (N padded 3->16), f16
    int t = tid - 327680;
    int e=t&7, lane=(t>>3)&63, kk=t>>9;
    int k = phi(kk, lane>>4, e);
    int n = lane&15;
    wlp[t] = (n<3) ? (f16)Wl[k*3+n] : (f16)0.f;
  } else if (tid < 335872){               // W0 columns + b0 in slot order, f32
    int t = tid - 331776;
    int e=t&7, lane=(t>>3)&63, kk=t>>9;
    int k = phi(kk, lane>>4, e);
    #pragma unroll
    for(int i=0;i<4;i++) w0p[t*4+i] = W0[i*256+k];
    b0p[t] = b0[k];
  } else if (tid < 348160){               // g_j = W0[j,:] @ Wh[0], slot order, f32
    int t = tid - 335872;
    int e=t&7, lane=(t>>3)&63, kk=(t>>9)&7, j=t>>12;
    int k = phi(kk, lane>>4, e);
    float acc = 0.f;
    for(int k0=0;k0<256;k0++) acc = fmaf(W0[j*256+k0], Wh[k0*256+k], acc);
    gp[t] = acc;
  } else if (tid < 368640){               // bh in D-layout order, f32
    int t = tid - 348160;
    int r=t&3, lane=(t>>2)&63, nt=(t>>8)&15, l=t>>12;
    bhp[t] = bh[l*256 + nt*16 + (lane>>4)*4 + r];
  }
}

// Lane-local mask layout (writer lane == reader lane), chunk XOR-swizzled.
__device__ __forceinline__ int moff(int lane, int kk){
  return lane*128 + ((kk ^ (lane & 7)) << 4);
}

// async global->LDS, 16B per lane; LDS dest is wave-uniform base + lane*16.
__device__ __forceinline__ void gload16(const void* g, void* l){
  __builtin_amdgcn_global_load_lds(
      (const __attribute__((address_space(1))) void*)g,
      (__attribute__((address_space(3))) void*)l, 16, 0, 0);
}
#define VMW4() asm volatile("s_waitcnt vmcnt(4)" ::: "memory")
#define VMW0() asm volatile("s_waitcnt vmcnt(0)" ::: "memory")
#define LGK0() asm volatile("s_waitcnt lgkmcnt(0)" ::: "memory")
#define BARRIER() do{ asm volatile("" ::: "memory"); __builtin_amdgcn_s_barrier(); \
                      asm volatile("" ::: "memory"); }while(0)

// R11: cooperative LDS weight staging. R9/R10 proved the wall is neither L2 BW
// (2-tile halving: -6%) nor per-wave reg prefetch (R10: 0%): it's the per-wave
// private L2 weight stream latency. All 4 waves consume IDENTICAL fragments in
// lockstep -> stage each layer's weights into LDS once per block (eighth-of-
// layer granularity, 2x16KB dbuf, counted vmcnt(4), raw barrier pairs).
// Weight path becomes ds_read_b128 (pipelined), L2 traffic /4, F-rings gone.
__global__ __launch_bounds__(256, 2) void velcurl(
    const float* __restrict__ x, const unsigned char* __restrict__ ws,
    float* __restrict__ out){
  __shared__ __align__(16) char wbuf[2][16384];    // staged weights: 16 frags/eighth
  __shared__ __align__(16) char mbuf[2][2][8192];  // [dbuf][tile] tanh' masks
  __shared__ float outt[2][3][3][16];              // [tile][j][n][s] Jacobian rows

  const int lane  = threadIdx.x & 63;
  const int w     = threadIdx.x >> 6;   // 0 = primal, 1..3 = tangent j=w-1
  const int s     = lane & 15;
  const int sbase = blockIdx.x << 5;    // 32 samples per block (2 tiles x 16)

  const f16x8* __restrict__ whp = (const f16x8*)(ws + OFF_WHP);
  const f16x8* __restrict__ wlp = (const f16x8*)(ws + OFF_WLP);
  const f32x4* __restrict__ w0p = (const f32x4*)(ws + OFF_W0P);
  const float* __restrict__ b0p = (const float*)(ws + OFF_B0P);
  const float* __restrict__ gp  = (const float*)(ws + OFF_GP);
  const f32x4* __restrict__ bhp = (const f32x4*)(ws + OFF_BHP);

  f16x8 st[2][8];    // per-tile current operand frags (B-slot order)
  f16x8 nst[2][8];   // per-tile next-state (primal h / raw tangent preact)

  #pragma unroll 1
  for(int p=0;p<5;p++){
    const f16x8* wl = whp + p*8192;     // layer-p fragment base
    // prologue: stage eighth 0 into wbuf[0] (4 frags per wave)
    #pragma unroll
    for(int i=0;i<4;i++)
      gload16((const void*)(wl + (w*4+i)*64 + lane), (void*)(&wbuf[0][0] + (w*4+i)*1024));

    // role prep (overlaps with stage flight)
    if (p==0){
      if (w==0){
        const f32x4 xv0 = ((const f32x4*)x)[sbase + s];
        const f32x4 xv1 = ((const f32x4*)x)[sbase + 16 + s];
        #pragma unroll
        for(int kk=0;kk<8;kk++){
          f16x8 v0, v1;
          #pragma unroll
          for(int e=0;e<8;e++){
            f32x4 wv = w0p[(kk*64+lane)*8+e];
            float b  = b0p[(kk*64+lane)*8+e];
            v0[e] = (f16)fmaf(xv0[3],wv[3], fmaf(xv0[2],wv[2], fmaf(xv0[1],wv[1], fmaf(xv0[0],wv[0], b))));
            v1[e] = (f16)fmaf(xv1[3],wv[3], fmaf(xv1[2],wv[2], fmaf(xv1[1],wv[1], fmaf(xv1[0],wv[0], b))));
          }
          st[0][kk] = v0; st[1][kk] = v1;
        }
      }
    } else if (w==0){
      #pragma unroll
      for(int kk=0;kk<8;kk++){ st[0][kk]=nst[0][kk]; st[1][kk]=nst[1][kk]; }
    } else {
      const char* mb0 = &mbuf[(p-1)&1][0][0];
      const char* mb1 = &mbuf[(p-1)&1][1][0];
      if (p==1){
        const int j = w-1;
        const f32x4* gpv = (const f32x4*)gp;
        #pragma unroll
        for(int kk=0;kk<8;kk++){
          f16x8 m80 = *(const f16x8*)(mb0 + moff(lane, kk));
          f16x8 m81 = *(const f16x8*)(mb1 + moff(lane, kk));
          f32x4 g0 = gpv[((j*8+kk)*64+lane)*2+0];
          f32x4 g1 = gpv[((j*8+kk)*64+lane)*2+1];
          f16x8 v0, v1;
          #pragma unroll
          for(int e=0;e<8;e++){
            float gv = (e<4) ? g0[e&3] : g1[e&3];
            v0[e] = (f16)((float)m80[e] * gv);
            v1[e] = (f16)((float)m81[e] * gv);
          }
          st[0][kk] = v0; st[1][kk] = v1;
        }
      } else {
        #pragma unroll
        for(int kk=0;kk<8;kk++){
          f16x8 m80 = *(const f16x8*)(mb0 + moff(lane, kk));
          f16x8 m81 = *(const f16x8*)(mb1 + moff(lane, kk));
          st[0][kk] = m80 * nst[0][kk];
          st[1][kk] = m81 * nst[1][kk];
        }
      }
    }

    // 8 eighths: [stage e+1 | wait e | barrier | compute e | barrier]
    #pragma unroll
    for(int e=0;e<8;e++){
      if (e<7){
        char* dst = &wbuf[(e+1)&1][0];
        #pragma unroll
        for(int i=0;i<4;i++)
          gload16((const void*)(wl + ((e+1)*16 + w*4+i)*64 + lane),
                  (void*)(dst + (w*4+i)*1024));
        VMW4();            // my 4 eighth-e loads done (newest 4 = e+1 in flight)
      } else {
        VMW0();
      }
      BARRIER();           // everyone's eighth-e fragments visible in LDS
      const f16x8* wb = (const f16x8*)&wbuf[e&1][0];
      if (w==0){
        const f32x4* bp = bhp + p*1024;
        f16x8 mc0, mc1;
        #pragma unroll
        for(int d=0;d<2;d++){
          const int nt = 2*e+d;
          f32x4 a0 = {0.f,0.f,0.f,0.f}, a1 = {0.f,0.f,0.f,0.f};
          #pragma unroll
          for(int kk=0;kk<8;kk++){
            f16x8 frag = wb[(d*8+kk)*64+lane];
            a0 = __builtin_amdgcn_mfma_f32_16x16x32_f16(frag, st[0][kk], a0, 0,0,0);
            a1 = __builtin_amdgcn_mfma_f32_16x16x32_f16(frag, st[1][kk], a1, 0,0,0);
          }
          f32x4 bv = bp[nt*64+lane];
          #pragma unroll
          for(int r=0;r<4;r++){
            float h0 = tanh_fast(a0[r]+bv[r]);
            float h1 = tanh_fast(a1[r]+bv[r]);
            nst[0][e][d*4+r] = (f16)h0;
            nst[1][e][d*4+r] = (f16)h1;
            mc0[d*4+r] = (f16)(1.f - h0*h0);
            mc1[d*4+r] = (f16)(1.f - h1*h1);
          }
          if (d==1){
            *(f16x8*)(&mbuf[p&1][0][0] + moff(lane, e)) = mc0;
            *(f16x8*)(&mbuf[p&1][1][0] + moff(lane, e)) = mc1;
          }
        }
      } else if (p>=1){
        #pragma unroll
        for(int d=0;d<2;d++){
          f32x4 a0 = {0.f,0.f,0.f,0.f}, a1 = {0.f,0.f,0.f,0.f};
          #pragma unroll
          for(int kk=0;kk<8;kk++){
            f16x8 frag = wb[(d*8+kk)*64+lane];
            a0 = __builtin_amdgcn_mfma_f32_16x16x32_f16(frag, st[0][kk], a0, 0,0,0);
            a1 = __builtin_amdgcn_mfma_f32_16x16x32_f16(frag, st[1][kk], a1, 0,0,0);
          }
          #pragma unroll
          for(int r=0;r<4;r++){
            nst[0][e][d*4+r] = (f16)a0[r];
            nst[1][e][d*4+r] = (f16)a1[r];
          }
        }
      }
      LGK0();              // mask ds_writes visible before release
      BARRIER();           // reads of wbuf[e&1] done before it is re-staged
    }
  }

  // ---- phase 5: tangent final (mask4 in mbuf[0]) -> Wl, rows to LDS ----
  if (w>0){
    const char* mb0 = &mbuf[0][0][0];
    const char* mb1 = &mbuf[0][1][0];
    f32x4 a0 = {0.f,0.f,0.f,0.f}, a1 = {0.f,0.f,0.f,0.f};
    #pragma unroll
    for(int kk=0;kk<8;kk++){
      f16x8 frag = wlp[kk*64+lane];
      f16x8 m80 = *(const f16x8*)(mb0 + moff(lane, kk));
      f16x8 m81 = *(const f16x8*)(mb1 + moff(lane, kk));
      a0 = __builtin_amdgcn_mfma_f32_16x16x32_f16(frag, m80 * nst[0][kk], a0, 0,0,0);
      a1 = __builtin_amdgcn_mfma_f32_16x16x32_f16(frag, m81 * nst[1][kk], a1, 0,0,0);
    }
    // D: col=lane&15=s, row=(lane>>4)*4+reg -> lanes 0..15 hold rows 0..3
    if (lane<16){
      outt[0][w-1][0][lane] = a0[0];
      outt[0][w-1][1][lane] = a0[1];
      outt[0][w-1][2][lane] = a0[2];
      outt[1][w-1][0][lane] = a1[0];
      outt[1][w-1][1][lane] = a1[1];
      outt[1][w-1][2][lane] = a1[2];
    }
  }
  LGK0();
  BARRIER();

  if (w==0 && lane<32){
    const int t = lane>>4, ss = lane&15;
    const int so = (sbase + lane)*3;
    out[so+0] = outt[t][1][2][ss] - outt[t][2][1][ss];  // da2/dx1 - da1/dx2
    out[so+1] = outt[t][2][0][ss] - outt[t][0][2][ss];  // da0/dx2 - da2/dx0
    out[so+2] = outt[t][0][1][ss] - outt[t][1][0][ss];  // da1/dx0 - da0/dx1
  }
}

extern "C" void kernel_launch(void* const* d_in, const int* in_sizes, int n_in,
                              void* d_out, int out_size, void* d_ws, size_t ws_size,
                              hipStream_t stream){
  const float* x  = (const float*)d_in[0];
  const float* W0 = (const float*)d_in[1];
  const float* b0 = (const float*)d_in[2];
  const float* Wh = (const float*)d_in[3];
  const float* bh = (const float*)d_in[4];
  const float* Wl = (const float*)d_in[5];
  // d_in[6] = bl: constant offset of a, curl kills it.
  prepack<<<1440, 256, 0, stream>>>(W0, b0, Wh, bh, Wl, (unsigned char*)d_ws);
  velcurl<<<2048, 256, 0, stream>>>(x, (const unsigned char*)d_ws, (float*)d_out);
}